// Round 11
// baseline (199.753 us; speedup 1.0000x reference)
//
#include <hip/hip_runtime.h>
#include <hip/hip_bf16.h>

#define NDIM 128
#define BDIM 131072
#define NMZI 8128                       // 128*127/2
#define NCHUNK 8                        // chunks of 16 whole sweeps
#define NJG 8                           // j-groups per block (scan groups)
#define NCOL 32                         // columns per block
#define NLOC 16                         // max local scan length = ceil(127/8)
static constexpr float CC = 0.70710678118654752440f;  // sqrt(0.5)

typedef __attribute__((ext_vector_type(8))) short bf16x8;
typedef __attribute__((ext_vector_type(4))) float f32x4;

// Static device scratch (d_ws size unknown -> don't touch it)
__device__ __align__(16) float2         g_V[NCHUNK * NDIM * NDIM];  // chunk partial unitaries
// Packed K=256 table for real-output GEMM: kg2<16 -> Ur[k=kg2*8+e][n]; kg2>=16 -> -Ui
__device__ __align__(16) unsigned short g_TB[32 * NDIM * 8];        // 64 KB
// Separate tables for the (unlikely) complex-interleaved output mode
__device__ __align__(16) unsigned short g_Ur[16 * NDIM * 8];
__device__ __align__(16) unsigned short g_Ui[16 * NDIM * 8];

__device__ inline unsigned short f2bf(float f) {
    union { __hip_bfloat16 h; unsigned short u; } cv;
    cv.h = __float2bfloat16(f);
    return cv.u;
}

// ---------------- K2: build chunk partial unitaries (sweep-aligned affine-scan) ----
// grid (4 col-slabs, NCHUNK=8) x 256 threads. Unchanged from R10 (verified).
__global__ __launch_bounds__(256) void build_scan(const float* __restrict__ mzi) {
    __shared__ float2 Usm[NDIM][NCOL];        // 32 KB
    __shared__ float4 ph[2][NDIM];            // 4 KB: cur/next sweep phases
    __shared__ float4 comp[NJG][NCOL];        // 4 KB
    const int tid   = threadIdx.x;
    const int c     = tid & 31;
    const int g     = tid >> 5;
    const int col0  = blockIdx.x * NCOL;
    const int chunk = blockIdx.y;
    const int i0    = chunk * 16;

    for (int k = g; k < NDIM; k += NJG)
        Usm[k][c] = make_float2((k == col0 + c) ? 1.f : 0.f, 0.f);

    const float2* mzp = (const float2*)mzi;   // (theta, phi) pairs
    int base = 127 * i0 - (i0 * (i0 - 1)) / 2;   // first step of sweep i0
    {
        const int L0 = NDIM - 1 - i0;
        if (tid < L0) {
            const float2 mz = mzp[base + tid];
            float sp, cp, st, ct;
            sincosf(mz.y, &sp, &cp);
            sincosf(mz.x, &st, &ct);
            ph[0][tid] = make_float4(cp, sp, CC * ct, CC * st);
        }
    }
    __syncthreads();

    #pragma unroll 1
    for (int sw = 0; sw < 16; ++sw) {
        const int i = i0 + sw;
        const int L = NDIM - 1 - i;               // sweep length
        if (L <= 0) break;
        const int cur = sw & 1;

        float2 mznext;
        const bool have = (sw < 15) && (tid < L - 1);
        if (have) mznext = mzp[base + L + tid];

        const float2 r0 = Usm[i][c];              // read BEFORE barrier
        const int nloc  = (L + NJG - 1) >> 3;
        const int myBeg = g * nloc;
        const int myN   = max(0, min(nloc, L - myBeg));

        float2 treg[NLOC];
        float2 qth[NLOC];
        float  A = 1.f;
        float2 Bc = make_float2(0.f, 0.f);
        #pragma unroll
        for (int kk = 0; kk < NLOC; ++kk) {
            if (kk < myN) {
                const int off = myBeg + kk;
                const float4 q  = ph[cur][off];
                const float2 rj = Usm[i + 1 + off][c];
                const float tr = fmaf(q.x, rj.x, -q.y * rj.y);
                const float ti = fmaf(q.x, rj.y,  q.y * rj.x);
                treg[kk] = make_float2(tr, ti);
                qth[kk]  = make_float2(q.z, q.w);
                Bc.x = CC * (Bc.x + tr);
                Bc.y = CC * (Bc.y + ti);
                A *= CC;
            }
        }
        comp[g][c] = make_float4(A, Bc.x, Bc.y, 0.f);
        __syncthreads();

        float2 r = r0;
        for (int h = 0; h < g; ++h) {
            const float4 cm = comp[h][c];
            r.x = fmaf(cm.x, r.x, cm.y);
            r.y = fmaf(cm.x, r.y, cm.z);
        }

        #pragma unroll
        for (int kk = 0; kk < NLOC; ++kk) {
            if (kk < myN) {
                const float2 t = treg[kk];
                const float2 q = qth[kk];
                const float dr = r.x - t.x, di = r.y - t.y;
                const float njx = fmaf(q.x, dr, -q.y * di);
                const float njy = fmaf(q.x, di,  q.y * dr);
                Usm[i + 1 + myBeg + kk][c] = make_float2(njx, njy);
                r.x = CC * (r.x + t.x);
                r.y = CC * (r.y + t.y);
            }
        }
        if (myN > 0 && (myBeg + myN == L))
            Usm[i][c] = r;

        if (have) {
            float sp, cp, st, ct;
            sincosf(mznext.y, &sp, &cp);
            sincosf(mznext.x, &st, &ct);
            ph[cur ^ 1][tid] = make_float4(cp, sp, CC * ct, CC * st);
        }
        __syncthreads();
        base += L;
    }

    float2* Vp = g_V + chunk * NDIM * NDIM;
    for (int k = g; k < NDIM; k += NJG)
        Vp[k * NDIM + col0 + c] = Usm[k][c];
}

// ---------------- K3: fused compose tree via row-chaining ----------------
// ONE kernel replaces compose(0), compose(1), compose_final.
// Block n computes row n of U = V7*V6*...*V0 as a vector-matrix chain:
//   v = row_n(V7);  for c = 6..0: v <- v * V_c;  U[n][:] = d_n * v.
// 256 threads = 2 k-halves x 128 columns; per level each half sums 64 k's
// (halved latency chain), halves combined via LDS.
__global__ __launch_bounds__(256) void compose_all(const float* __restrict__ oph) {
    __shared__ float2 vbuf[NDIM];
    __shared__ float2 part[2][NDIM];
    const int tid = threadIdx.x;
    const int m   = tid & 127;
    const int h   = tid >> 7;
    const int n   = blockIdx.x;

    if (h == 0) vbuf[m] = g_V[7 * NDIM * NDIM + n * NDIM + m];
    __syncthreads();

    #pragma unroll 1
    for (int c = 6; c >= 0; --c) {
        const float2* Vc = g_V + c * NDIM * NDIM;
        float cr = 0.f, ci = 0.f;
        #pragma unroll 16
        for (int k0 = 0; k0 < 64; ++k0) {
            const int k = h * 64 + k0;
            const float2 a = vbuf[k];            // LDS broadcast
            const float2 b = Vc[k * NDIM + m];   // coalesced 1KB/row
            cr = fmaf(a.x, b.x, fmaf(-a.y, b.y, cr));
            ci = fmaf(a.x, b.y, fmaf( a.y, b.x, ci));
        }
        part[h][m] = make_float2(cr, ci);
        __syncthreads();
        if (h == 0) {
            const float2 p0 = part[0][m], p1 = part[1][m];
            vbuf[m] = make_float2(p0.x + p1.x, p0.y + p1.y);
        }
        __syncthreads();
    }

    if (h == 0) {
        const float2 u = vbuf[m];
        float ds, dc;
        sincosf(oph[n], &ds, &dc);
        const float vr = fmaf(u.x, dc, -u.y * ds);
        const float vi = fmaf(u.x, ds,  u.y * dc);
        const int kg = m >> 3, e = m & 7;
        g_TB[(kg * NDIM + n) * 8 + e]        = f2bf(vr);
        g_TB[((16 + kg) * NDIM + n) * 8 + e] = f2bf(-vi);
        g_Ur[(kg * NDIM + n) * 8 + e] = f2bf(vr);
        g_Ui[(kg * NDIM + n) * 8 + e] = f2bf(vi);
    }
}

// ---------------- K5a: real-output GEMM (out_size == B*N, f32 real part) ----------------
// R10 structure (verified: WRITE=64MB, absmax 0.03125) + 2 tiles/wave:
// tile1's NT loads issue before tile0's MFMA/store so HBM latency hides
// under compute. Single wave-private 8KB LDS buffer reused across both
// tiles (per-wave DS ordering => no barriers). 1024 blocks x 4 waves.
#define XLOAD(G, R)                                                             \
    {                                                                           \
        const f32x4* sre_ = (const f32x4*)(xr + (size_t)(R) * NDIM);            \
        const f32x4* sim_ = (const f32x4*)(xi + (size_t)(R) * NDIM);            \
        _Pragma("unroll")                                                       \
        for (int p_ = 0; p_ < 8; ++p_)                                          \
            G[p_] = __builtin_nontemporal_load(sre_ + p_ * 64 + lane);          \
        _Pragma("unroll")                                                       \
        for (int p_ = 0; p_ < 8; ++p_)                                          \
            G[8 + p_] = __builtin_nontemporal_load(sim_ + p_ * 64 + lane);      \
    }

#define XSTAGE(G)                                                               \
    {                                                                           \
        _Pragma("unroll")                                                       \
        for (int p_ = 0; p_ < 8; ++p_) {                                        \
            const int row_ = 2 * p_ + lh;                                       \
            const int swz_ = (row_ & 7) << 4;                                   \
            uint2 v_;                                                           \
            v_.x = ((unsigned)f2bf(G[p_][1]) << 16) | f2bf(G[p_][0]);           \
            v_.y = ((unsigned)f2bf(G[p_][3]) << 16) | f2bf(G[p_][2]);           \
            *(uint2*)(buf + row_ * 512 + ((l31 * 8) ^ swz_)) = v_;              \
            v_.x = ((unsigned)f2bf(G[8 + p_][1]) << 16) | f2bf(G[8 + p_][0]);   \
            v_.y = ((unsigned)f2bf(G[8 + p_][3]) << 16) | f2bf(G[8 + p_][2]);   \
            *(uint2*)(buf + row_ * 512 + 256 + ((l31 * 8) ^ swz_)) = v_;        \
        }                                                                       \
    }

#define XFRAGS(fx)                                                              \
    {                                                                           \
        _Pragma("unroll")                                                       \
        for (int kc_ = 0; kc_ < 8; ++kc_) {                                     \
            const int off_ = (((kc_ & 3) * 64 + kg4 * 16) ^ rswz)               \
                             + ((kc_ >= 4) ? 256 : 0);                          \
            fx[kc_] = *(const bf16x8*)(buf + r15 * 512 + off_);                 \
        }                                                                       \
    }

#define XCOMPUTE(fx, R)                                                         \
    {                                                                           \
        _Pragma("unroll")                                                       \
        for (int nt_ = 0; nt_ < 8; ++nt_) {                                     \
            f32x4 a0_ = {0.f, 0.f, 0.f, 0.f};                                   \
            f32x4 a1_ = {0.f, 0.f, 0.f, 0.f};                                   \
            _Pragma("unroll")                                                   \
            for (int kc_ = 0; kc_ < 4; ++kc_)                                   \
                a0_ = __builtin_amdgcn_mfma_f32_16x16x32_bf16(                  \
                    gT[(kc_ * 4 + kg4) * NDIM + nt_ * 16 + r15], fx[kc_], a0_, 0, 0, 0); \
            _Pragma("unroll")                                                   \
            for (int kc_ = 4; kc_ < 8; ++kc_)                                   \
                a1_ = __builtin_amdgcn_mfma_f32_16x16x32_bf16(                  \
                    gT[(kc_ * 4 + kg4) * NDIM + nt_ * 16 + r15], fx[kc_], a1_, 0, 0, 0); \
            const f32x4 s_ = a0_ + a1_;                                         \
            *(f32x4*)(buf + r15 * 512 + ((nt_ * 64 + kg4 * 16) ^ rswz)) = s_;   \
        }                                                                       \
        char* outp_ = (char*)(out + (size_t)(R) * NDIM);                        \
        _Pragma("unroll")                                                       \
        for (int p_ = 0; p_ < 8; ++p_) {                                        \
            const int bofs_ = p_ * 1024 + lane * 16;                            \
            const int row_  = bofs_ >> 9;                                       \
            const int colb_ = bofs_ & 511;                                      \
            const f32x4 v_ = *(const f32x4*)(buf + row_ * 512 +                 \
                                (colb_ ^ ((row_ & 7) << 4)));                   \
            __builtin_nontemporal_store(v_, (f32x4*)(outp_ + bofs_));           \
        }                                                                       \
    }

__global__ __launch_bounds__(256) void cmatmul0(const float* __restrict__ xr,
                                                const float* __restrict__ xi,
                                                float* __restrict__ out) {
    __shared__ __align__(16) char smX[4][8192];   // per-wave tile buffer
    const int tid  = threadIdx.x;
    const int lane = tid & 63;
    const int w    = tid >> 6;
    const int r15  = lane & 15;
    const int kg4  = lane >> 4;
    const int l31  = lane & 31;
    const int lh   = lane >> 5;
    const int rswz = (r15 & 7) << 4;
    const int R0   = blockIdx.x * 128 + w * 16;   // tile-0 base row
    const int R1   = R0 + 64;                     // tile-1 base row

    char* buf = &smX[w][0];
    const bf16x8* gT = (const bf16x8*)g_TB;

    float4 Gt[16];   // named float4 to keep XLOAD types consistent
    f32x4* G = (f32x4*)Gt;

    XLOAD(G, R0)                 // tile 0 loads
    XSTAGE(G)                    // waits on loads, stage to LDS
    bf16x8 fx[8];
    XFRAGS(fx)                   // tile-0 fragments in regs; G dead
    XLOAD(G, R1)                 // issue tile-1 loads (hide under compute)
    XCOMPUTE(fx, R0)             // tile-0 MFMA + stash + contiguous NT store
    XSTAGE(G)                    // tile-1 stage (waits its loads)
    XFRAGS(fx)
    XCOMPUTE(fx, R1)             // tile-1 compute + store
}

// ---------------- K5b: complex-output fallback (bf16 re,im pairs) ----------------
__global__ __launch_bounds__(256) void cmatmul1(const float* __restrict__ xr,
                                                const float* __restrict__ xi,
                                                ushort2* __restrict__ outp) {
    const int lane  = threadIdx.x & 63;
    const int w     = threadIdx.x >> 6;
    const int btile = blockIdx.x * 64 + w * 16;
    const int r15   = lane & 15;
    const int kg4   = lane >> 4;
    const int bload = btile + r15;

    const bf16x8* Ur = (const bf16x8*)g_Ur;
    const bf16x8* Ui = (const bf16x8*)g_Ui;
    const float* xrp = xr + (size_t)bload * NDIM;
    const float* xip = xi + (size_t)bload * NDIM;

    bf16x8 ar[4], ai[4], ain[4];
    #pragma unroll
    for (int kc = 0; kc < 4; ++kc) {
        const int k0 = kc * 32 + kg4 * 8;
        float4 rlo = *(const float4*)(xrp + k0);
        float4 rhi = *(const float4*)(xrp + k0 + 4);
        float4 ilo = *(const float4*)(xip + k0);
        float4 ihi = *(const float4*)(xip + k0 + 4);
        bf16x8 vr, vi, vn;
        vr[0] = (short)f2bf(rlo.x); vr[1] = (short)f2bf(rlo.y);
        vr[2] = (short)f2bf(rlo.z); vr[3] = (short)f2bf(rlo.w);
        vr[4] = (short)f2bf(rhi.x); vr[5] = (short)f2bf(rhi.y);
        vr[6] = (short)f2bf(rhi.z); vr[7] = (short)f2bf(rhi.w);
        vi[0] = (short)f2bf(ilo.x); vi[1] = (short)f2bf(ilo.y);
        vi[2] = (short)f2bf(ilo.z); vi[3] = (short)f2bf(ilo.w);
        vi[4] = (short)f2bf(ihi.x); vi[5] = (short)f2bf(ihi.y);
        vi[6] = (short)f2bf(ihi.z); vi[7] = (short)f2bf(ihi.w);
        #pragma unroll
        for (int e = 0; e < 8; ++e) vn[e] = (short)(vi[e] ^ 0x8000);
        ar[kc] = vr; ai[kc] = vi; ain[kc] = vn;
    }

    #pragma unroll
    for (int nt = 0; nt < 8; ++nt) {
        f32x4 accR = {0.f, 0.f, 0.f, 0.f};
        f32x4 accI = {0.f, 0.f, 0.f, 0.f};
        #pragma unroll
        for (int kc = 0; kc < 4; ++kc) {
            const int kg = kc * 4 + kg4;
            bf16x8 br = Ur[kg * NDIM + nt * 16 + r15];
            bf16x8 bi = Ui[kg * NDIM + nt * 16 + r15];
            accR = __builtin_amdgcn_mfma_f32_16x16x32_bf16(ar[kc],  br, accR, 0, 0, 0);
            accR = __builtin_amdgcn_mfma_f32_16x16x32_bf16(ain[kc], bi, accR, 0, 0, 0);
            accI = __builtin_amdgcn_mfma_f32_16x16x32_bf16(ar[kc],  bi, accI, 0, 0, 0);
            accI = __builtin_amdgcn_mfma_f32_16x16x32_bf16(ai[kc],  br, accI, 0, 0, 0);
        }
        const int n    = nt * 16 + r15;
        const int brow = btile + kg4 * 4;
        #pragma unroll
        for (int r = 0; r < 4; ++r)
            outp[(size_t)(brow + r) * NDIM + n] = make_ushort2(f2bf(accR[r]), f2bf(accI[r]));
    }
}

extern "C" void kernel_launch(void* const* d_in, const int* in_sizes, int n_in,
                              void* d_out, int out_size, void* d_ws, size_t ws_size,
                              hipStream_t stream) {
    const float* xr  = (const float*)d_in[0];
    const float* xi  = (const float*)d_in[1];
    const float* mzi = (const float*)d_in[2];
    const float* oph = (const float*)d_in[3];

    build_scan<<<dim3(4, NCHUNK), dim3(256), 0, stream>>>(mzi);
    compose_all<<<dim3(NDIM), dim3(256), 0, stream>>>(oph);
    if (out_size == BDIM * NDIM) {
        cmatmul0<<<dim3(BDIM / 128), dim3(256), 0, stream>>>(xr, xi, (float*)d_out);
    } else {
        cmatmul1<<<dim3(BDIM / 64), dim3(256), 0, stream>>>(xr, xi, (ushort2*)d_out);
    }
}

// Round 12
// 125.210 us; speedup vs baseline: 1.5953x; 1.5953x over previous
//
#include <hip/hip_runtime.h>
#include <hip/hip_bf16.h>

#define NDIM 128
#define N2   (NDIM * NDIM)
#define BDIM 131072
#define NMZI 8128                       // 128*127/2
#define NCHUNK 8                        // chunks of 16 whole sweeps
#define NJG 8                           // j-groups per block (scan groups)
#define NCOL 32                         // columns per block
#define NLOC 16                         // max local scan length = ceil(127/8)
static constexpr float CC = 0.70710678118654752440f;  // sqrt(0.5)

typedef __attribute__((ext_vector_type(8))) short bf16x8;
typedef __attribute__((ext_vector_type(4))) float f32x4;

// Static device scratch (d_ws size unknown -> don't touch it)
// NOTE: declaration order matters for the compose 8-row B-prefetch overrun:
// g_V -> g_W -> g_Y are adjacent-ish; every B operand has a successor array.
__device__ __align__(16) float2         g_V[NCHUNK * N2];   // chunk partial unitaries
__device__ __align__(16) float2         g_W[4 * N2];        // compose level 0 out
__device__ __align__(16) float2         g_Y[2 * N2];        // compose level 1 out
// Packed K=256 table for real-output GEMM: kg2<16 -> Ur[k=kg2*8+e][n]; kg2>=16 -> -Ui
__device__ __align__(16) unsigned short g_TB[32 * NDIM * 8];        // 64 KB
// Separate tables for the (unlikely) complex-interleaved output mode
__device__ __align__(16) unsigned short g_Ur[16 * NDIM * 8];
__device__ __align__(16) unsigned short g_Ui[16 * NDIM * 8];

__device__ inline unsigned short f2bf(float f) {
    union { __hip_bfloat16 h; unsigned short u; } cv;
    cv.h = __float2bfloat16(f);
    return cv.u;
}

// ---------------- K2: build chunk partial unitaries (sweep-aligned affine-scan) ----
// grid (4 col-slabs, NCHUNK=8) x 256 threads. Unchanged from R10 (verified).
__global__ __launch_bounds__(256) void build_scan(const float* __restrict__ mzi) {
    __shared__ float2 Usm[NDIM][NCOL];        // 32 KB
    __shared__ float4 ph[2][NDIM];            // 4 KB: cur/next sweep phases
    __shared__ float4 comp[NJG][NCOL];        // 4 KB
    const int tid   = threadIdx.x;
    const int c     = tid & 31;
    const int g     = tid >> 5;
    const int col0  = blockIdx.x * NCOL;
    const int chunk = blockIdx.y;
    const int i0    = chunk * 16;

    for (int k = g; k < NDIM; k += NJG)
        Usm[k][c] = make_float2((k == col0 + c) ? 1.f : 0.f, 0.f);

    const float2* mzp = (const float2*)mzi;   // (theta, phi) pairs
    int base = 127 * i0 - (i0 * (i0 - 1)) / 2;   // first step of sweep i0
    {
        const int L0 = NDIM - 1 - i0;
        if (tid < L0) {
            const float2 mz = mzp[base + tid];
            float sp, cp, st, ct;
            sincosf(mz.y, &sp, &cp);
            sincosf(mz.x, &st, &ct);
            ph[0][tid] = make_float4(cp, sp, CC * ct, CC * st);
        }
    }
    __syncthreads();

    #pragma unroll 1
    for (int sw = 0; sw < 16; ++sw) {
        const int i = i0 + sw;
        const int L = NDIM - 1 - i;               // sweep length
        if (L <= 0) break;
        const int cur = sw & 1;

        float2 mznext;
        const bool have = (sw < 15) && (tid < L - 1);
        if (have) mznext = mzp[base + L + tid];

        const float2 r0 = Usm[i][c];              // read BEFORE barrier
        const int nloc  = (L + NJG - 1) >> 3;
        const int myBeg = g * nloc;
        const int myN   = max(0, min(nloc, L - myBeg));

        float2 treg[NLOC];
        float2 qth[NLOC];
        float  A = 1.f;
        float2 Bc = make_float2(0.f, 0.f);
        #pragma unroll
        for (int kk = 0; kk < NLOC; ++kk) {
            if (kk < myN) {
                const int off = myBeg + kk;
                const float4 q  = ph[cur][off];
                const float2 rj = Usm[i + 1 + off][c];
                const float tr = fmaf(q.x, rj.x, -q.y * rj.y);
                const float ti = fmaf(q.x, rj.y,  q.y * rj.x);
                treg[kk] = make_float2(tr, ti);
                qth[kk]  = make_float2(q.z, q.w);
                Bc.x = CC * (Bc.x + tr);
                Bc.y = CC * (Bc.y + ti);
                A *= CC;
            }
        }
        comp[g][c] = make_float4(A, Bc.x, Bc.y, 0.f);
        __syncthreads();

        float2 r = r0;
        for (int h = 0; h < g; ++h) {
            const float4 cm = comp[h][c];
            r.x = fmaf(cm.x, r.x, cm.y);
            r.y = fmaf(cm.x, r.y, cm.z);
        }

        #pragma unroll
        for (int kk = 0; kk < NLOC; ++kk) {
            if (kk < myN) {
                const float2 t = treg[kk];
                const float2 q = qth[kk];
                const float dr = r.x - t.x, di = r.y - t.y;
                const float njx = fmaf(q.x, dr, -q.y * di);
                const float njy = fmaf(q.x, di,  q.y * dr);
                Usm[i + 1 + myBeg + kk][c] = make_float2(njx, njy);
                r.x = CC * (r.x + t.x);
                r.y = CC * (r.y + t.y);
            }
        }
        if (myN > 0 && (myBeg + myN == L))
            Usm[i][c] = r;

        if (have) {
            float sp, cp, st, ct;
            sincosf(mznext.y, &sp, &cp);
            sincosf(mznext.x, &st, &ct);
            ph[cur ^ 1][tid] = make_float4(cp, sp, CC * ct, CC * st);
        }
        __syncthreads();
        base += L;
    }

    float2* Vp = g_V + chunk * N2;
    for (int k = g; k < NDIM; k += NJG)
        Vp[k * NDIM + col0 + c] = Usm[k][c];
}

// ---------------- K3: compose tree level (latency-pipelined) ----------------
// level 0: W[p] = V[2p+1]*V[2p], p<4 ; level 1: Y[q] = W[2q+1]*W[2q], q<2.
// grid (32 row-groups, nprod) x 128 threads. Block computes 4 output rows.
// A-rows staged in LDS (broadcast); B streamed with 8-deep NAMED-register
// prefetch (8 loads in flight covers ~200cy L2 latency). Each thread: 4
// complex accumulators = 8 independent fma chains. B-prefetch overruns 8
// rows past the matrix end -> lands in the adjacent device array (safe).
#define CFMA(acc, av, b)                                                    \
    acc.x = fmaf(av.x, b.x, fmaf(-av.y, b.y, acc.x));                       \
    acc.y = fmaf(av.x, b.y, fmaf( av.y, b.x, acc.y));

__global__ __launch_bounds__(128) void compose(int level) {
    const int p  = blockIdx.y;
    const int n0 = blockIdx.x * 4;
    const int m  = threadIdx.x;
    const float2* A; const float2* B; float2* Cout;
    if (level == 0) {
        A = g_V + (2 * p + 1) * N2;  B = g_V + (2 * p) * N2;  Cout = g_W + p * N2;
    } else {
        A = g_W + (2 * p + 1) * N2;  B = g_W + (2 * p) * N2;  Cout = g_Y + p * N2;
    }
    __shared__ float2 As[4][NDIM];
    #pragma unroll
    for (int r = 0; r < 4; ++r) As[r][m] = A[(n0 + r) * NDIM + m];
    __syncthreads();

    float2 a0 = {0.f, 0.f}, a1 = {0.f, 0.f}, a2 = {0.f, 0.f}, a3 = {0.f, 0.f};
    float2 bb[8];
    #pragma unroll
    for (int u = 0; u < 8; ++u) bb[u] = B[u * NDIM + m];

    #pragma unroll 1
    for (int k0 = 0; k0 < NDIM; k0 += 8) {
        #pragma unroll
        for (int u = 0; u < 8; ++u) {
            const float2 b = bb[u];
            bb[u] = B[(k0 + 8 + u) * NDIM + m];   // last-iter overrun: safe
            const int k = k0 + u;
            const float2 v0 = As[0][k]; CFMA(a0, v0, b)
            const float2 v1 = As[1][k]; CFMA(a1, v1, b)
            const float2 v2 = As[2][k]; CFMA(a2, v2, b)
            const float2 v3 = As[3][k]; CFMA(a3, v3, b)
        }
    }
    Cout[(n0 + 0) * NDIM + m] = a0;
    Cout[(n0 + 1) * NDIM + m] = a1;
    Cout[(n0 + 2) * NDIM + m] = a2;
    Cout[(n0 + 3) * NDIM + m] = a3;
}

// ---------------- K4: final compose U = Y1*Y0, diag, emit packed bf16 ----------------
// Same 4-row pipelined structure; then applies diag and packs tables.
__global__ __launch_bounds__(128) void compose_final(const float* __restrict__ oph) {
    const int n0 = blockIdx.x * 4;
    const int m  = threadIdx.x;
    const float2* A = g_Y + N2;   // Y1 (left)
    const float2* B = g_Y;        // Y0 (right; overrun lands in Y1)
    __shared__ float2 As[4][NDIM];
    #pragma unroll
    for (int r = 0; r < 4; ++r) As[r][m] = A[(n0 + r) * NDIM + m];
    __syncthreads();

    float2 a0 = {0.f, 0.f}, a1 = {0.f, 0.f}, a2 = {0.f, 0.f}, a3 = {0.f, 0.f};
    float2 bb[8];
    #pragma unroll
    for (int u = 0; u < 8; ++u) bb[u] = B[u * NDIM + m];

    #pragma unroll 1
    for (int k0 = 0; k0 < NDIM; k0 += 8) {
        #pragma unroll
        for (int u = 0; u < 8; ++u) {
            const float2 b = bb[u];
            bb[u] = B[(k0 + 8 + u) * NDIM + m];
            const int k = k0 + u;
            const float2 v0 = As[0][k]; CFMA(a0, v0, b)
            const float2 v1 = As[1][k]; CFMA(a1, v1, b)
            const float2 v2 = As[2][k]; CFMA(a2, v2, b)
            const float2 v3 = As[3][k]; CFMA(a3, v3, b)
        }
    }

    const int kg = m >> 3, e = m & 7;
    #pragma unroll
    for (int r = 0; r < 4; ++r) {
        const int n = n0 + r;
        const float2 u = (r == 0) ? a0 : (r == 1) ? a1 : (r == 2) ? a2 : a3;
        float ds, dc;
        sincosf(oph[n], &ds, &dc);
        const float vr = fmaf(u.x, dc, -u.y * ds);
        const float vi = fmaf(u.x, ds,  u.y * dc);
        g_TB[(kg * NDIM + n) * 8 + e]        = f2bf(vr);
        g_TB[((16 + kg) * NDIM + n) * 8 + e] = f2bf(-vi);
        g_Ur[(kg * NDIM + n) * 8 + e] = f2bf(vr);
        g_Ui[(kg * NDIM + n) * 8 + e] = f2bf(vi);
    }
}

// ---------------- K5a: real-output GEMM (out_size == B*N, f32 real part) ----------------
// R11 2-tile structure (verified absmax 0.03125).
#define XLOAD(G, R)                                                             \
    {                                                                           \
        const f32x4* sre_ = (const f32x4*)(xr + (size_t)(R) * NDIM);            \
        const f32x4* sim_ = (const f32x4*)(xi + (size_t)(R) * NDIM);            \
        _Pragma("unroll")                                                       \
        for (int p_ = 0; p_ < 8; ++p_)                                          \
            G[p_] = __builtin_nontemporal_load(sre_ + p_ * 64 + lane);          \
        _Pragma("unroll")                                                       \
        for (int p_ = 0; p_ < 8; ++p_)                                          \
            G[8 + p_] = __builtin_nontemporal_load(sim_ + p_ * 64 + lane);      \
    }

#define XSTAGE(G)                                                               \
    {                                                                           \
        _Pragma("unroll")                                                       \
        for (int p_ = 0; p_ < 8; ++p_) {                                        \
            const int row_ = 2 * p_ + lh;                                       \
            const int swz_ = (row_ & 7) << 4;                                   \
            uint2 v_;                                                           \
            v_.x = ((unsigned)f2bf(G[p_][1]) << 16) | f2bf(G[p_][0]);           \
            v_.y = ((unsigned)f2bf(G[p_][3]) << 16) | f2bf(G[p_][2]);           \
            *(uint2*)(buf + row_ * 512 + ((l31 * 8) ^ swz_)) = v_;              \
            v_.x = ((unsigned)f2bf(G[8 + p_][1]) << 16) | f2bf(G[8 + p_][0]);   \
            v_.y = ((unsigned)f2bf(G[8 + p_][3]) << 16) | f2bf(G[8 + p_][2]);   \
            *(uint2*)(buf + row_ * 512 + 256 + ((l31 * 8) ^ swz_)) = v_;        \
        }                                                                       \
    }

#define XFRAGS(fx)                                                              \
    {                                                                           \
        _Pragma("unroll")                                                       \
        for (int kc_ = 0; kc_ < 8; ++kc_) {                                     \
            const int off_ = (((kc_ & 3) * 64 + kg4 * 16) ^ rswz)               \
                             + ((kc_ >= 4) ? 256 : 0);                          \
            fx[kc_] = *(const bf16x8*)(buf + r15 * 512 + off_);                 \
        }                                                                       \
    }

#define XCOMPUTE(fx, R)                                                         \
    {                                                                           \
        _Pragma("unroll")                                                       \
        for (int nt_ = 0; nt_ < 8; ++nt_) {                                     \
            f32x4 a0_ = {0.f, 0.f, 0.f, 0.f};                                   \
            f32x4 a1_ = {0.f, 0.f, 0.f, 0.f};                                   \
            _Pragma("unroll")                                                   \
            for (int kc_ = 0; kc_ < 4; ++kc_)                                   \
                a0_ = __builtin_amdgcn_mfma_f32_16x16x32_bf16(                  \
                    gT[(kc_ * 4 + kg4) * NDIM + nt_ * 16 + r15], fx[kc_], a0_, 0, 0, 0); \
            _Pragma("unroll")                                                   \
            for (int kc_ = 4; kc_ < 8; ++kc_)                                   \
                a1_ = __builtin_amdgcn_mfma_f32_16x16x32_bf16(                  \
                    gT[(kc_ * 4 + kg4) * NDIM + nt_ * 16 + r15], fx[kc_], a1_, 0, 0, 0); \
            const f32x4 s_ = a0_ + a1_;                                         \
            *(f32x4*)(buf + r15 * 512 + ((nt_ * 64 + kg4 * 16) ^ rswz)) = s_;   \
        }                                                                       \
        char* outp_ = (char*)(out + (size_t)(R) * NDIM);                        \
        _Pragma("unroll")                                                       \
        for (int p_ = 0; p_ < 8; ++p_) {                                        \
            const int bofs_ = p_ * 1024 + lane * 16;                            \
            const int row_  = bofs_ >> 9;                                       \
            const int colb_ = bofs_ & 511;                                      \
            const f32x4 v_ = *(const f32x4*)(buf + row_ * 512 +                 \
                                (colb_ ^ ((row_ & 7) << 4)));                   \
            __builtin_nontemporal_store(v_, (f32x4*)(outp_ + bofs_));           \
        }                                                                       \
    }

__global__ __launch_bounds__(256) void cmatmul0(const float* __restrict__ xr,
                                                const float* __restrict__ xi,
                                                float* __restrict__ out) {
    __shared__ __align__(16) char smX[4][8192];   // per-wave tile buffer
    const int tid  = threadIdx.x;
    const int lane = tid & 63;
    const int w    = tid >> 6;
    const int r15  = lane & 15;
    const int kg4  = lane >> 4;
    const int l31  = lane & 31;
    const int lh   = lane >> 5;
    const int rswz = (r15 & 7) << 4;
    const int R0   = blockIdx.x * 128 + w * 16;   // tile-0 base row
    const int R1   = R0 + 64;                     // tile-1 base row

    char* buf = &smX[w][0];
    const bf16x8* gT = (const bf16x8*)g_TB;

    float4 Gt[16];
    f32x4* G = (f32x4*)Gt;

    XLOAD(G, R0)                 // tile 0 loads
    XSTAGE(G)                    // waits on loads, stage to LDS
    bf16x8 fx[8];
    XFRAGS(fx)                   // tile-0 fragments in regs; G dead
    XLOAD(G, R1)                 // issue tile-1 loads (hide under compute)
    XCOMPUTE(fx, R0)             // tile-0 MFMA + stash + contiguous NT store
    XSTAGE(G)                    // tile-1 stage (waits its loads)
    XFRAGS(fx)
    XCOMPUTE(fx, R1)             // tile-1 compute + store
}

// ---------------- K5b: complex-output fallback (bf16 re,im pairs) ----------------
__global__ __launch_bounds__(256) void cmatmul1(const float* __restrict__ xr,
                                                const float* __restrict__ xi,
                                                ushort2* __restrict__ outp) {
    const int lane  = threadIdx.x & 63;
    const int w     = threadIdx.x >> 6;
    const int btile = blockIdx.x * 64 + w * 16;
    const int r15   = lane & 15;
    const int kg4   = lane >> 4;
    const int bload = btile + r15;

    const bf16x8* Ur = (const bf16x8*)g_Ur;
    const bf16x8* Ui = (const bf16x8*)g_Ui;
    const float* xrp = xr + (size_t)bload * NDIM;
    const float* xip = xi + (size_t)bload * NDIM;

    bf16x8 ar[4], ai[4], ain[4];
    #pragma unroll
    for (int kc = 0; kc < 4; ++kc) {
        const int k0 = kc * 32 + kg4 * 8;
        float4 rlo = *(const float4*)(xrp + k0);
        float4 rhi = *(const float4*)(xrp + k0 + 4);
        float4 ilo = *(const float4*)(xip + k0);
        float4 ihi = *(const float4*)(xip + k0 + 4);
        bf16x8 vr, vi, vn;
        vr[0] = (short)f2bf(rlo.x); vr[1] = (short)f2bf(rlo.y);
        vr[2] = (short)f2bf(rlo.z); vr[3] = (short)f2bf(rlo.w);
        vr[4] = (short)f2bf(rhi.x); vr[5] = (short)f2bf(rhi.y);
        vr[6] = (short)f2bf(rhi.z); vr[7] = (short)f2bf(rhi.w);
        vi[0] = (short)f2bf(ilo.x); vi[1] = (short)f2bf(ilo.y);
        vi[2] = (short)f2bf(ilo.z); vi[3] = (short)f2bf(ilo.w);
        vi[4] = (short)f2bf(ihi.x); vi[5] = (short)f2bf(ihi.y);
        vi[6] = (short)f2bf(ihi.z); vi[7] = (short)f2bf(ihi.w);
        #pragma unroll
        for (int e = 0; e < 8; ++e) vn[e] = (short)(vi[e] ^ 0x8000);
        ar[kc] = vr; ai[kc] = vi; ain[kc] = vn;
    }

    #pragma unroll
    for (int nt = 0; nt < 8; ++nt) {
        f32x4 accR = {0.f, 0.f, 0.f, 0.f};
        f32x4 accI = {0.f, 0.f, 0.f, 0.f};
        #pragma unroll
        for (int kc = 0; kc < 4; ++kc) {
            const int kg = kc * 4 + kg4;
            bf16x8 br = Ur[kg * NDIM + nt * 16 + r15];
            bf16x8 bi = Ui[kg * NDIM + nt * 16 + r15];
            accR = __builtin_amdgcn_mfma_f32_16x16x32_bf16(ar[kc],  br, accR, 0, 0, 0);
            accR = __builtin_amdgcn_mfma_f32_16x16x32_bf16(ain[kc], bi, accR, 0, 0, 0);
            accI = __builtin_amdgcn_mfma_f32_16x16x32_bf16(ar[kc],  bi, accI, 0, 0, 0);
            accI = __builtin_amdgcn_mfma_f32_16x16x32_bf16(ai[kc],  br, accI, 0, 0, 0);
        }
        const int n    = nt * 16 + r15;
        const int brow = btile + kg4 * 4;
        #pragma unroll
        for (int r = 0; r < 4; ++r)
            outp[(size_t)(brow + r) * NDIM + n] = make_ushort2(f2bf(accR[r]), f2bf(accI[r]));
    }
}

extern "C" void kernel_launch(void* const* d_in, const int* in_sizes, int n_in,
                              void* d_out, int out_size, void* d_ws, size_t ws_size,
                              hipStream_t stream) {
    const float* xr  = (const float*)d_in[0];
    const float* xi  = (const float*)d_in[1];
    const float* mzi = (const float*)d_in[2];
    const float* oph = (const float*)d_in[3];

    build_scan<<<dim3(4, NCHUNK), dim3(256), 0, stream>>>(mzi);
    compose<<<dim3(32, 4), dim3(128), 0, stream>>>(0);
    compose<<<dim3(32, 2), dim3(128), 0, stream>>>(1);
    compose_final<<<dim3(32), dim3(128), 0, stream>>>(oph);
    if (out_size == BDIM * NDIM) {
        cmatmul0<<<dim3(BDIM / 128), dim3(256), 0, stream>>>(xr, xi, (float*)d_out);
    } else {
        cmatmul1<<<dim3(BDIM / 64), dim3(256), 0, stream>>>(xr, xi, (ushort2*)d_out);
    }
}